// Round 4
// baseline (33.500 us; speedup 1.0000x reference)
//
#include <hip/hip_runtime.h>

#define NB 8
#define NT 2048
#define ND 1024
#define NS 512
#define NW 16

typedef float f32x4 __attribute__((ext_vector_type(4)));

// One block per (b, s) span. 256 threads; thread t owns d = 4t .. 4t+3.
// XCD swizzle: b = blockIdx & 7 pins all 512 spans of batch b to one XCD ->
// gathers touch only text[b] (8 MB) instead of 64 MB.
// Register pin: the 16 gathered row fragments are forced to stay in VGPRs
// across the barrier (empty asm "modifies" them), so the pooling loop reuses
// them instead of the compiler re-issuing all 16 gathers (observed at
// VGPR_Count=60: rows were rematerialized -> 2x gather traffic).
__global__ __launch_bounds__(256) void span_attn_kernel(
    const float* __restrict__ text,   // [B, T, D]
    const int*   __restrict__ wi,     // [B, S, W] word_indices
    const int*   __restrict__ wm,     // [B, S, W] word_mask
    const int*   __restrict__ wim,    // [B, S]    word_indices_mask
    const float* __restrict__ att_w,  // [D]
    const float* __restrict__ att_b,  // [1]
    float*       __restrict__ out)    // [B, S, D]
{
    const int b    = blockIdx.x & (NB - 1);   // XCD-aligned batch
    const int s    = blockIdx.x >> 3;
    const int bs   = b * NS + s;
    const int tid  = threadIdx.x;             // 0 .. 255
    const int lane = tid & 63;
    const int wave = tid >> 6;

    __shared__ float red[4][NW];

    // Uniform per-span metadata.
    const int* wip = wi + (size_t)bs * NW;
    const int* wmp = wm + (size_t)bs * NW;

    int   idx[NW];
    float mk[NW];
    #pragma unroll
    for (int w = 0; w < NW; ++w) {
        int v  = wip[w];
        idx[w] = v > 0 ? v : 0;               // relu clamp, matches reference
        mk[w]  = (float)wmp[w];
    }

    const float4 w4   = *reinterpret_cast<const float4*>(att_w + tid * 4);
    const float  bias = att_b[0];

    const float* tb = text + (size_t)b * NT * ND + tid * 4;

    // Gather 16 row fragments into registers; compute partial logits.
    float4 row[NW];
    float  p[NW];
    #pragma unroll
    for (int w = 0; w < NW; ++w) {
        row[w] = *reinterpret_cast<const float4*>(tb + (size_t)idx[w] * ND);
        p[w]   = row[w].x * w4.x + row[w].y * w4.y
               + row[w].z * w4.z + row[w].w * w4.w;
    }

    // Pin the row fragments in VGPRs: opaque "modification" prevents the
    // compiler from rematerializing the gathers after the barrier.
    #pragma unroll
    for (int w = 0; w < NW; ++w) {
        asm volatile("" : "+v"(row[w].x), "+v"(row[w].y),
                          "+v"(row[w].z), "+v"(row[w].w));
    }

    // 64-lane butterfly reduce each of the 16 partials.
    #pragma unroll
    for (int w = 0; w < NW; ++w) {
        float v = p[w];
        v += __shfl_xor(v, 1);
        v += __shfl_xor(v, 2);
        v += __shfl_xor(v, 4);
        v += __shfl_xor(v, 8);
        v += __shfl_xor(v, 16);
        v += __shfl_xor(v, 32);
        p[w] = v;
    }
    if (lane < NW) red[wave][lane] = p[lane];
    __syncthreads();

    // Every thread reconstructs the 16 full logits (broadcast LDS reads).
    float logit[NW];
    #pragma unroll
    for (int w = 0; w < NW; ++w)
        logit[w] = red[0][w] + red[1][w] + red[2][w] + red[3][w] + bias;

    // Masked softmax over W, replicating reference -1e9 + post-mask semantics.
    float ml[NW];
    float m = -3.0e38f;
    #pragma unroll
    for (int w = 0; w < NW; ++w) {
        ml[w] = (mk[w] != 0.0f) ? logit[w] : -1.0e9f;
        m = fmaxf(m, ml[w]);
    }
    float e[NW];
    float sum = 0.0f;
    #pragma unroll
    for (int w = 0; w < NW; ++w) {
        e[w] = expf(ml[w] - m);
        sum += e[w];
    }
    const float inv = 1.0f / sum;

    // Weighted-sum pooling over the register-resident row fragments.
    float4 acc = make_float4(0.f, 0.f, 0.f, 0.f);
    #pragma unroll
    for (int w = 0; w < NW; ++w) {
        const float wgt = e[w] * inv * mk[w];
        acc.x += wgt * row[w].x;
        acc.y += wgt * row[w].y;
        acc.z += wgt * row[w].z;
        acc.w += wgt * row[w].w;
    }

    const float sm = (float)wim[bs];
    acc.x *= sm; acc.y *= sm; acc.z *= sm; acc.w *= sm;

    // Non-temporal store: don't let the 16 MB output evict text from L2.
    f32x4 accv;
    accv.x = acc.x; accv.y = acc.y; accv.z = acc.z; accv.w = acc.w;
    __builtin_nontemporal_store(accv,
        reinterpret_cast<f32x4*>(out + (size_t)bs * ND + tid * 4));
}

extern "C" void kernel_launch(void* const* d_in, const int* in_sizes, int n_in,
                              void* d_out, int out_size, void* d_ws, size_t ws_size,
                              hipStream_t stream) {
    const float* text  = (const float*)d_in[0];
    // d_in[1] = contextualized_embedding: unused by the reference.
    const int*   wi    = (const int*)d_in[2];
    const int*   wm    = (const int*)d_in[3];
    const int*   wim   = (const int*)d_in[4];
    const float* att_w = (const float*)d_in[5];
    const float* att_b = (const float*)d_in[6];
    float*       out   = (float*)d_out;

    dim3 grid(NB * NS);
    dim3 block(256);
    span_attn_kernel<<<grid, block, 0, stream>>>(text, wi, wm, wim, att_w, att_b, out);
}

// Round 5
// 31.028 us; speedup vs baseline: 1.0797x; 1.0797x over previous
//
#include <hip/hip_runtime.h>

#define NB 8
#define NT 2048
#define ND 1024
#define NS 512
#define NW 16

typedef float f32x4 __attribute__((ext_vector_type(4)));

// One block per (b, s) span; 256 threads.
// Phase 1: thread (w = tid>>4, j = tid&15) gathers row w's chunk ONCE
//          (16 x float4 at cols j*4 + k*64), dot-partials vs att_w, and
//          stages the row into LDS as packed bf16 (32 KB tile).
// Reduce:  1 partial/thread -> 4 shuffle steps over the 16-lane j-group
//          (vs 96 shuffle ops in the per-thread-16-logit form).
// Phase 2: after one barrier, redundant 16-wide softmax (f32 logits), then
//          each thread pools its 4 output cols from the bf16 LDS tile.
// Single global gather (268 MB logical) instead of double (536 MB).
__global__ __launch_bounds__(256, 4) void span_attn_kernel(
    const float* __restrict__ text,   // [B, T, D]
    const int*   __restrict__ wi,     // [B, S, W]
    const int*   __restrict__ wm,     // [B, S, W]
    const int*   __restrict__ wim,    // [B, S]
    const float* __restrict__ att_w,  // [D]
    const float* __restrict__ att_b,  // [1]
    float*       __restrict__ out)    // [B, S, D]
{
    const int b   = blockIdx.x & (NB - 1);   // XCD-aligned batch
    const int s   = blockIdx.x >> 3;
    const int bs  = b * NS + s;
    const int tid = threadIdx.x;
    const int w   = tid >> 4;                // row 0..15
    const int j   = tid & 15;                // col-group 0..15

    __shared__ unsigned int ldsrow[NW][ND / 2];  // bf16 pairs, 32 KB
    __shared__ float red[NW];

    const int* wip = wi + (size_t)bs * NW;
    const int* wmp = wm + (size_t)bs * NW;

    // Own row index (relu clamp).
    int v = wip[w];
    const int myidx = v > 0 ? v : 0;

    const float* src = text + ((size_t)b * NT + (size_t)myidx) * ND;

    // ---- Phase 1: gather row w once; dot-partial + bf16 pack to LDS ----
    float4 frag[16];
    #pragma unroll
    for (int k = 0; k < 16; ++k)
        frag[k] = *reinterpret_cast<const float4*>(src + j * 4 + k * 64);

    float partial = 0.0f;
    #pragma unroll
    for (int k = 0; k < 16; ++k) {
        const float4 wv = *reinterpret_cast<const float4*>(att_w + j * 4 + k * 64);
        partial += frag[k].x * wv.x + frag[k].y * wv.y
                 + frag[k].z * wv.z + frag[k].w * wv.w;
        // pack 4 f32 -> 2 u32 of bf16 (round-to-nearest-ish)
        unsigned int x0 = __float_as_uint(frag[k].x) + 0x8000u;
        unsigned int x1 = __float_as_uint(frag[k].y) + 0x8000u;
        unsigned int x2 = __float_as_uint(frag[k].z) + 0x8000u;
        unsigned int x3 = __float_as_uint(frag[k].w) + 0x8000u;
        uint2 q;
        q.x = (x0 >> 16) | (x1 & 0xFFFF0000u);
        q.y = (x2 >> 16) | (x3 & 0xFFFF0000u);
        *reinterpret_cast<uint2*>(&ldsrow[w][j * 2 + k * 32]) = q;
    }

    // Reduce partial over the 16-lane j-group (xor 1,2,4,8 stays in-group).
    partial += __shfl_xor(partial, 1);
    partial += __shfl_xor(partial, 2);
    partial += __shfl_xor(partial, 4);
    partial += __shfl_xor(partial, 8);
    if (j == 0) red[w] = partial;

    // Per-thread mask vector (broadcast loads).
    float mk[NW];
    #pragma unroll
    for (int q4 = 0; q4 < 4; ++q4) {
        const int4 mv = *reinterpret_cast<const int4*>(wmp + q4 * 4);
        mk[q4 * 4 + 0] = (float)mv.x;
        mk[q4 * 4 + 1] = (float)mv.y;
        mk[q4 * 4 + 2] = (float)mv.z;
        mk[q4 * 4 + 3] = (float)mv.w;
    }
    const float bias = att_b[0];

    __syncthreads();

    // ---- Softmax over W (every thread, redundant; f32 logits) ----
    float ml[NW];
    float m = -3.0e38f;
    #pragma unroll
    for (int ww = 0; ww < NW; ++ww) {
        const float lg = red[ww] + bias;
        ml[ww] = (mk[ww] != 0.0f) ? lg : -1.0e9f;
        m = fmaxf(m, ml[ww]);
    }
    float e[NW];
    float sum = 0.0f;
    #pragma unroll
    for (int ww = 0; ww < NW; ++ww) {
        e[ww] = __expf(ml[ww] - m);
        sum += e[ww];
    }
    const float inv = 1.0f / sum;

    // ---- Phase 2: pool 4 output cols from the bf16 tile ----
    float4 acc = make_float4(0.f, 0.f, 0.f, 0.f);
    #pragma unroll
    for (int ww = 0; ww < NW; ++ww) {
        const uint2 q = *reinterpret_cast<const uint2*>(&ldsrow[ww][tid * 2]);
        const float f0 = __uint_as_float(q.x << 16);
        const float f1 = __uint_as_float(q.x & 0xFFFF0000u);
        const float f2 = __uint_as_float(q.y << 16);
        const float f3 = __uint_as_float(q.y & 0xFFFF0000u);
        const float wgt = e[ww] * inv * mk[ww];
        acc.x += wgt * f0;
        acc.y += wgt * f1;
        acc.z += wgt * f2;
        acc.w += wgt * f3;
    }

    const float sm = (float)wim[bs];
    f32x4 accv;
    accv.x = acc.x * sm; accv.y = acc.y * sm;
    accv.z = acc.z * sm; accv.w = acc.w * sm;
    __builtin_nontemporal_store(accv,
        reinterpret_cast<f32x4*>(out + (size_t)bs * ND + tid * 4));
}

extern "C" void kernel_launch(void* const* d_in, const int* in_sizes, int n_in,
                              void* d_out, int out_size, void* d_ws, size_t ws_size,
                              hipStream_t stream) {
    const float* text  = (const float*)d_in[0];
    // d_in[1] = contextualized_embedding: unused by the reference.
    const int*   wi    = (const int*)d_in[2];
    const int*   wm    = (const int*)d_in[3];
    const int*   wim   = (const int*)d_in[4];
    const float* att_w = (const float*)d_in[5];
    const float* att_b = (const float*)d_in[6];
    float*       out   = (float*)d_out;

    dim3 grid(NB * NS);
    dim3 block(256);
    span_attn_kernel<<<grid, block, 0, stream>>>(text, wi, wm, wim, att_w, att_b, out);
}